// Round 1
// baseline (1084.353 us; speedup 1.0000x reference)
//
#include <hip/hip_runtime.h>
#include <hip/hip_bf16.h>

#define HID 512
#define ENCD 512
#define NB 256
#define SEQ 1024
#define M_TOTAL (NB * SEQ)  // 262144

typedef short bf16x8 __attribute__((ext_vector_type(8)));
typedef float floatx4 __attribute__((ext_vector_type(4)));

__device__ __forceinline__ unsigned short f2bf(float f) {
    unsigned u = __builtin_bit_cast(unsigned, f);
    u += 0x7FFFu + ((u >> 16) & 1u);   // round-to-nearest-even
    return (unsigned short)(u >> 16);
}

// ---------------------------------------------------------------------------
// Kernel 1: proj_h = dh @ W_h^T (fp32), W_s -> bf16 conversion
// grid 256 (one block per batch row), 256 threads
// ---------------------------------------------------------------------------
__global__ __launch_bounds__(256) void prep_kernel(
    const float* __restrict__ dh,      // [256][512]
    const float* __restrict__ W_h,     // [512][512] (h, e)
    const float* __restrict__ W_s,     // [512][512] (h, e)
    float* __restrict__ proj_h,        // [256][512]
    unsigned short* __restrict__ Ws_bf)// [512][512] bf16
{
    __shared__ float sdh[HID];
    const int b = blockIdx.x;
    const int t = threadIdx.x;

    float2 d2 = ((const float2*)(dh + b * HID))[t];
    sdh[2 * t]     = d2.x;
    sdh[2 * t + 1] = d2.y;

    // W_s bf16 conversion: 65536 float4 across 256*256 threads -> 1 each
    {
        int f4 = b * 256 + t;
        float4 w = ((const float4*)W_s)[f4];
        ushort4 o;
        o.x = f2bf(w.x); o.y = f2bf(w.y); o.z = f2bf(w.z); o.w = f2bf(w.w);
        ((ushort4*)Ws_bf)[f4] = o;
    }
    __syncthreads();

    #pragma unroll
    for (int i = 0; i < 2; ++i) {
        const int h = t + i * 256;
        const float4* wr = (const float4*)(W_h + (size_t)h * HID);
        float acc = 0.f;
        #pragma unroll 8
        for (int e4 = 0; e4 < HID / 4; ++e4) {
            float4 w = wr[e4];
            float4 s = ((const float4*)sdh)[e4];
            acc += w.x * s.x + w.y * s.y + w.z * s.z + w.w * s.w;
        }
        proj_h[b * HID + h] = acc;
    }
}

// ---------------------------------------------------------------------------
// Kernel 2: fused score GEMM.
// scores[m] = sum_h v[h] * tanh(proj_h[b][h] + sum_e enc[m][e]*W_s[h][e])
// Block: 128 M-rows x ALL 512 N-cols, 512 threads (8 waves), wave tile 64x128.
// A (enc) staged fp32->bf16 via LDS; B (Ws bf16) fragments straight from L2.
// ---------------------------------------------------------------------------
__global__ __launch_bounds__(512, 2) void score_gemm(
    const float* __restrict__ enc,          // [262144][512] fp32
    const unsigned short* __restrict__ Ws,  // [512][512] bf16 (h, e)
    const float* __restrict__ proj_h,       // [256][512]
    const float* __restrict__ v,            // [512]
    float* __restrict__ scores)             // [256][1024]
{
    __shared__ unsigned short sA[128 * 40]; // [m][k], stride 40 bf16 (pad 8)
    __shared__ float sred[4][128];

    const int t    = threadIdx.x;
    const int wave = t >> 6;
    const int lane = t & 63;
    const int ln15 = lane & 15;
    const int lk   = lane >> 4;          // 0..3, k-chunk selector
    const int m0   = blockIdx.x * 128;   // 1024 % 128 == 0 -> single batch b
    const int bb   = m0 >> 10;
    const int wm   = (wave & 1) * 64;    // wave M offset
    const int wn   = (wave >> 1) * 128;  // wave N offset

    floatx4 acc[4][8] = {};

    // B fragment base: lane reads 8 bf16 at row (wn + nj*16 + ln15), col lk*8
    const unsigned short* wsrow = Ws + (size_t)(wn + ln15) * HID + lk * 8;

    for (int kt = 0; kt < 16; ++kt) {
        const int k0 = kt * 32;

        // B fragments for this K-slab, direct from global (L2-resident, 512KB)
        bf16x8 bfrag[8];
        #pragma unroll
        for (int nj = 0; nj < 8; ++nj)
            bfrag[nj] = *(const bf16x8*)(wsrow + (size_t)nj * 16 * HID + k0);

        __syncthreads();  // protect sA from previous iteration's readers
        // Stage A tile 128x32 fp32 -> bf16: 1024 float4, 2 per thread
        #pragma unroll
        for (int i = 0; i < 2; ++i) {
            const int f  = i * 512 + t;
            const int r  = f >> 3;
            const int c4 = f & 7;
            float4 a = *(const float4*)(enc + (size_t)(m0 + r) * ENCD + k0 + c4 * 4);
            ushort4 o;
            o.x = f2bf(a.x); o.y = f2bf(a.y); o.z = f2bf(a.z); o.w = f2bf(a.w);
            *(ushort4*)(&sA[r * 40 + c4 * 4]) = o;
        }
        __syncthreads();

        #pragma unroll
        for (int mi = 0; mi < 4; ++mi) {
            bf16x8 afrag = *(const bf16x8*)(&sA[(wm + mi * 16 + ln15) * 40 + lk * 8]);
            #pragma unroll
            for (int nj = 0; nj < 8; ++nj)
                acc[mi][nj] = __builtin_amdgcn_mfma_f32_16x16x32_bf16(
                    afrag, bfrag[nj], acc[mi][nj], 0, 0, 0);
        }
    }

    // Epilogue: tanh + v-dot, reduce over N.
    // C layout: col = lane&15, row = (lane>>4)*4 + reg
    float phv[8], vv[8];
    #pragma unroll
    for (int nj = 0; nj < 8; ++nj) {
        const int n = wn + nj * 16 + ln15;
        phv[nj] = proj_h[bb * HID + n];
        vv[nj]  = v[n];
    }

    #pragma unroll
    for (int mi = 0; mi < 4; ++mi) {
        #pragma unroll
        for (int r = 0; r < 4; ++r) {
            float s = 0.f;
            #pragma unroll
            for (int nj = 0; nj < 8; ++nj) {
                float x = acc[mi][nj][r] + phv[nj];
                float e = __expf(2.f * x);
                float th = 1.f - 2.f / (e + 1.f);  // tanh, saturates safely
                s += vv[nj] * th;
            }
            // reduce across the 16 column-lanes (ln15)
            s += __shfl_xor(s, 8, 64);
            s += __shfl_xor(s, 4, 64);
            s += __shfl_xor(s, 2, 64);
            s += __shfl_xor(s, 1, 64);
            if (ln15 == 0) {
                const int row = wm + mi * 16 + lk * 4 + r;
                sred[wave >> 1][row] = s;
            }
        }
    }
    __syncthreads();
    if (t < 128)
        scores[m0 + t] = sred[0][t] + sred[1][t] + sred[2][t] + sred[3][t];
}

// ---------------------------------------------------------------------------
// Kernel 3: softmax over L, then context = alpha^T enc. One block per batch.
// ---------------------------------------------------------------------------
__global__ __launch_bounds__(512) void softmax_ctx(
    const float* __restrict__ scores,  // [256][1024]
    const float* __restrict__ enc,     // [256][1024][512]
    float* __restrict__ ctx_out,       // [256][512]
    float* __restrict__ alpha_out)     // [256][1024]
{
    __shared__ float salpha[SEQ];
    __shared__ float sbufA[8], sbufB[8];
    const int b = blockIdx.x;
    const int t = threadIdx.x;
    const int w = t >> 6;

    float2 sc = ((const float2*)(scores + (size_t)b * SEQ))[t];

    float mx = fmaxf(sc.x, sc.y);
    #pragma unroll
    for (int m = 32; m >= 1; m >>= 1) mx = fmaxf(mx, __shfl_xor(mx, m, 64));
    if ((t & 63) == 0) sbufA[w] = mx;
    __syncthreads();
    float gm = sbufA[0];
    #pragma unroll
    for (int i = 1; i < 8; ++i) gm = fmaxf(gm, sbufA[i]);

    float e0 = __expf(sc.x - gm);
    float e1 = __expf(sc.y - gm);
    float ssum = e0 + e1;
    #pragma unroll
    for (int m = 32; m >= 1; m >>= 1) ssum += __shfl_xor(ssum, m, 64);
    if ((t & 63) == 0) sbufB[w] = ssum;
    __syncthreads();
    float tot = 0.f;
    #pragma unroll
    for (int i = 0; i < 8; ++i) tot += sbufB[i];
    const float inv = 1.f / tot;

    const float a0 = e0 * inv, a1 = e1 * inv;
    salpha[2 * t]     = a0;
    salpha[2 * t + 1] = a1;
    ((float2*)(alpha_out + (size_t)b * SEQ))[t] = make_float2(a0, a1);
    __syncthreads();

    // context: thread t owns column e = t
    float acc = 0.f;
    const float* ep = enc + (size_t)b * SEQ * ENCD + t;
    #pragma unroll 8
    for (int l = 0; l < SEQ; ++l)
        acc += salpha[l] * ep[(size_t)l * ENCD];
    ctx_out[(size_t)b * ENCD + t] = acc;
}

// ---------------------------------------------------------------------------
extern "C" void kernel_launch(void* const* d_in, const int* in_sizes, int n_in,
                              void* d_out, int out_size, void* d_ws, size_t ws_size,
                              hipStream_t stream) {
    const float* dh  = (const float*)d_in[0];  // decoder_hidden [256][512]
    const float* enc = (const float*)d_in[1];  // encoder_outputs [256][1024][512]
    const float* W_h = (const float*)d_in[2];  // [512][512]
    const float* W_s = (const float*)d_in[3];  // [512][512]
    const float* v   = (const float*)d_in[4];  // [1][512]

    float* ws = (float*)d_ws;
    float* proj_h = ws;                                // 131072 floats
    float* scores = ws + 131072;                       // 262144 floats
    unsigned short* Ws_bf = (unsigned short*)(ws + 131072 + 262144); // 262144 bf16

    float* ctx   = (float*)d_out;              // [256][512]
    float* alpha = (float*)d_out + NB * HID;   // [256][1024]

    prep_kernel<<<NB, 256, 0, stream>>>(dh, W_h, W_s, proj_h, Ws_bf);
    score_gemm<<<M_TOTAL / 128, 512, 0, stream>>>(enc, Ws_bf, proj_h, v, scores);
    softmax_ctx<<<NB, 512, 0, stream>>>(scores, enc, ctx, alpha);
}